// Round 6
// baseline (840.373 us; speedup 1.0000x reference)
//
#include <hip/hip_runtime.h>
#include <math.h>

// Radial NUFFT + Pipe-Menon density compensation, MI355X (gfx950).
// bf16 MFMA (16x16x32), 2-term hi/lo split (3 products). Round 6 = round-5
// (verified) + adj restructure ONLY: 32x32 wave tiles / 256-thread blocks
// (occupancy 2->~4 waves/SIMD), register-double-buffered A+scalar prefetch,
// slot-based (non-atomic) LDS reduction epilogue.

#define MTOT 36864      // N_SHOTS*N_SAMPLES == NPIX*NPIX
#define NPIX 192
#define SPLITS 128
#define MPS (MTOT / SPLITS)     // 288 m per split
#define ADJ_CHUNKS (MPS / 16)   // 18 chunks of 32 K

typedef __attribute__((ext_vector_type(8))) short s16x8;
typedef __attribute__((ext_vector_type(4))) float f32x4;
typedef __attribute__((ext_vector_type(4))) unsigned u32x4;

__device__ __forceinline__ f32x4 mfma_bf16(u32x4 a, u32x4 b, f32x4 c) {
    return __builtin_amdgcn_mfma_f32_16x16x32_bf16(
        __builtin_bit_cast(s16x8, a), __builtin_bit_cast(s16x8, b), c, 0, 0, 0);
}

// Split (a,b) into packed bf16 pairs: hi = (bf16(a) | bf16(b)<<16), lo = residuals.
__device__ __forceinline__ void split_pk(float a, float b, unsigned &hi, unsigned &lo) {
    const unsigned ua = __float_as_uint(a), ub = __float_as_uint(b);
    const unsigned ha = (ua + 0x8000u) & 0xffff0000u;
    const unsigned hb = (ub + 0x8000u) & 0xffff0000u;
    hi = (ha >> 16) | hb;
    const float la = a - __uint_as_float(ha);
    const float lb = b - __uint_as_float(hb);
    lo = ((__float_as_uint(la) + 0x8000u) >> 16) |
         ((__float_as_uint(lb) + 0x8000u) & 0xffff0000u);
}

// k split into 12-bit hi + residual so kh*p (p integer, |p|<=96) is EXACT in fp32.
__device__ __forceinline__ void ksplit(float k, float &kh, float &kl) {
    kh = __uint_as_float(__float_as_uint(k) & 0xfffff000u);
    kl = k - kh;
}
__device__ __forceinline__ float redphase(float kh, float kl, float p) {
    float r = kh * p;
    r -= rintf(r);
    r = fmaf(kl, p, r);
    return r;                   // revolutions, |r| <= ~0.512
}
__device__ __forceinline__ unsigned rot16(unsigned v) {
    return __builtin_amdgcn_alignbit(v, v, 16);
}

// ---------------------------------------------------------------------------
// Precompute A = (cos, -sin) packed bf16 hi/lo in fragment layout [x][m].
__global__ void precompA_k(const float* __restrict__ traj,
                           unsigned* __restrict__ Aph, unsigned* __restrict__ Apl) {
    const int m = blockIdx.x * 256 + threadIdx.x;
    const int x = blockIdx.y;
    float kh, kl; ksplit(traj[2 * m], kh, kl);
    const float ph = redphase(kh, kl, (float)(x - 96));
    const float c = __builtin_amdgcn_cosf(ph);
    const float s = __builtin_amdgcn_sinf(ph);
    unsigned h, l; split_pk(c, -s, h, l);
    Aph[(size_t)x * MTOT + m] = h;
    Apl[(size_t)x * MTOT + m] = l;
}

__global__ void winit_k(float* __restrict__ wr, float* __restrict__ wi) {
    const int m = blockIdx.x * 256 + threadIdx.x;
    wr[m] = 1.f; wi[m] = 0.f;
}

// ---------------------------------------------------------------------------
// Adjoint: out[x,y] += sum_m conj(A[m,x]) * d[m] * conj(B[m,y])
// 32x32 tile per wave (2x2 MFMA subtiles); 4 waves = 4 K-splits per block.
// A-frags + traj/d scalars register-double-buffered (prefetch next chunk).
// Epilogue: 2-slot non-atomic LDS reduction, then one global atomic/elem/block.
__global__ __launch_bounds__(256, 4) void adj_mfma_k(
    const float* __restrict__ traj,
    const float* __restrict__ dre, const float* __restrict__ dim_,
    const unsigned* __restrict__ Aph, const unsigned* __restrict__ Apl,
    float* __restrict__ outRe, float* __restrict__ outIm)
{
    __shared__ float red[2 * 2048];                // 2 slots x (2 planes x 32 x 32)
    const int tid = threadIdx.x;
    const int lane = tid & 63, wid = tid >> 6;     // wid 0..3
    const int l15 = lane & 15, q = lane >> 4;
    const int tile = blockIdx.x;                   // 0..35 (6x6 of 32x32)
    const int tx = (tile % 6) * 32, ty = (tile / 6) * 32;
    const int s = blockIdx.y * 4 + wid;            // split 0..127

    f32x4 accRe[2][2], accIm[2][2];
    #pragma unroll
    for (int i = 0; i < 2; ++i)
        #pragma unroll
        for (int j = 0; j < 2; ++j) {
            accRe[i][j] = (f32x4){0.f, 0.f, 0.f, 0.f};
            accIm[i][j] = (f32x4){0.f, 0.f, 0.f, 0.f};
        }

    const float pyB = (float)(ty + l15 - 96);
    const int mrow = s * MPS;

    u32x4 Ah[2][2], Al[2][2];                      // [buf][si]
    float kyb[2][4], drb[2][4], dib[2][4];         // [buf][r]

    {   // load chunk 0 into buffer 0
        const int mb = mrow + q * 4;
        #pragma unroll
        for (int si = 0; si < 2; ++si) {
            const size_t off = (size_t)(tx + si * 16 + l15) * MTOT + mb;
            Ah[0][si] = *(const u32x4*)(Aph + off);
            Al[0][si] = *(const u32x4*)(Apl + off);
        }
        #pragma unroll
        for (int r = 0; r < 4; ++r) {
            kyb[0][r] = traj[2 * (mb + r) + 1];
            drb[0][r] = dre[mb + r];
            dib[0][r] = dim_[mb + r];
        }
    }

    for (int ch = 0; ch < ADJ_CHUNKS; ++ch) {
        const int cur = ch & 1, nxt = cur ^ 1;
        {   // prefetch next chunk (clamped reload on the last iteration)
            const int chn = (ch + 1 < ADJ_CHUNKS) ? ch + 1 : ch;
            const int mbn = mrow + chn * 16 + q * 4;
            #pragma unroll
            for (int si = 0; si < 2; ++si) {
                const size_t off = (size_t)(tx + si * 16 + l15) * MTOT + mbn;
                Ah[nxt][si] = *(const u32x4*)(Aph + off);
                Al[nxt][si] = *(const u32x4*)(Apl + off);
            }
            #pragma unroll
            for (int r = 0; r < 4; ++r) {
                kyb[nxt][r] = traj[2 * (mbn + r) + 1];
                drb[nxt][r] = dre[mbn + r];
                dib[nxt][r] = dim_[mbn + r];
            }
        }

        float ur[4], ui[4], ryc[4], rys[4];
        #pragma unroll
        for (int r = 0; r < 4; ++r) {
            const float ky = kyb[cur][r];
            const float dr_ = drb[cur][r], di_ = dib[cur][r];
            float kh, kl;
            ksplit(ky, kh, kl);
            const float ph = redphase(kh, kl, pyB);
            const float cb = __builtin_amdgcn_cosf(ph), sb = __builtin_amdgcn_sinf(ph);
            // u = d*conj(B): u_re = dr*c - di*s ; u_im = di*c + dr*s
            ur[r] = dr_ * cb - di_ * sb;
            ui[r] = di_ * cb + dr_ * sb;
            float g = ky * 16.f; g -= rintf(g);
            ryc[r] = __builtin_amdgcn_cosf(g); rys[r] = __builtin_amdgcn_sinf(g);
        }
        #pragma unroll
        for (int sj = 0; sj < 2; ++sj) {
            u32x4 Ph, Pl, Qh, Ql;
            #pragma unroll
            for (int r = 0; r < 4; ++r) {
                unsigned h, l; split_pk(ur[r], ui[r], h, l);
                Ph[r] = h; Pl[r] = l;
                Qh[r] = rot16(h) ^ 0x80000000u;           // (u_im, -u_re)
                Ql[r] = rot16(l) ^ 0x80000000u;
                // u advances by e^{+i2pi*16ky} (conj(B) has +i)
                const float nr = ur[r] * ryc[r] - ui[r] * rys[r];
                const float ni = ui[r] * ryc[r] + ur[r] * rys[r];
                ur[r] = nr; ui[r] = ni;
            }
            #pragma unroll
            for (int si = 0; si < 2; ++si) {
                accRe[si][sj] = mfma_bf16(Ah[cur][si], Ph, accRe[si][sj]);
                accRe[si][sj] = mfma_bf16(Ah[cur][si], Pl, accRe[si][sj]);
                accRe[si][sj] = mfma_bf16(Al[cur][si], Ph, accRe[si][sj]);
                accIm[si][sj] = mfma_bf16(Ah[cur][si], Qh, accIm[si][sj]);
                accIm[si][sj] = mfma_bf16(Ah[cur][si], Ql, accIm[si][sj]);
                accIm[si][sj] = mfma_bf16(Al[cur][si], Qh, accIm[si][sj]);
            }
        }
    }

    // 2-slot non-atomic reduction: waves 0,1 store; waves 2,3 add; fold.
    float* slot = red + (wid & 1) * 2048;
    if (wid < 2) {
        #pragma unroll
        for (int si = 0; si < 2; ++si)
            #pragma unroll
            for (int sj = 0; sj < 2; ++sj)
                #pragma unroll
                for (int rg = 0; rg < 4; ++rg) {
                    const int idx = (si * 16 + q * 4 + rg) * 32 + sj * 16 + l15;
                    slot[idx]        = accRe[si][sj][rg];
                    slot[1024 + idx] = accIm[si][sj][rg];
                }
    }
    __syncthreads();
    if (wid >= 2) {
        #pragma unroll
        for (int si = 0; si < 2; ++si)
            #pragma unroll
            for (int sj = 0; sj < 2; ++sj)
                #pragma unroll
                for (int rg = 0; rg < 4; ++rg) {
                    const int idx = (si * 16 + q * 4 + rg) * 32 + sj * 16 + l15;
                    slot[idx]        += accRe[si][sj][rg];
                    slot[1024 + idx] += accIm[si][sj][rg];
                }
    }
    __syncthreads();
    for (int e = tid; e < 2048; e += 256) {
        const float v = red[e] + red[2048 + e];
        const int p = e >> 10, rem = e & 1023;
        const int xl = rem >> 5, yl = rem & 31;
        float* dst = p ? outIm : outRe;
        atomicAdd(dst + (tx + xl) * NPIX + (ty + yl), v);
    }
}

// ---------------------------------------------------------------------------
// fwdq: q[m] = sum_x A[m,x] * (sum_y B[m,y]*g[x,y]).   (unchanged from r5)
__device__ __forceinline__ void fw_stage_load(const unsigned* __restrict__ Ghi,
                                              const unsigned* __restrict__ Glo,
                                              int tid, int koff, u32x4 st[3]) {
    #pragma unroll
    for (int j = 0; j < 3; ++j) {
        const int li = tid + j * 576;
        if (li < 1536) {
            const int row = li >> 3, pl = (li >> 2) & 1, qt = li & 3;
            const unsigned* src = pl ? Glo : Ghi;
            st[j] = *(const u32x4*)(src + row * 192 + koff + qt * 4);
        }
    }
}
__device__ __forceinline__ void fw_stage_write(unsigned* sb, int tid, const u32x4 st[3]) {
    #pragma unroll
    for (int j = 0; j < 3; ++j) {
        const int li = tid + j * 576;
        if (li < 1536) {
            const int row = li >> 3, pl = (li >> 2) & 1, qt = li & 3;
            *(u32x4*)(sb + pl * 3840 + row * 20 + qt * 4) = st[j];
        }
    }
}

__global__ __launch_bounds__(576) void fwdq_k(
    const float* __restrict__ traj,
    const unsigned* __restrict__ Ghi, const unsigned* __restrict__ Glo,
    float* __restrict__ wre, float* __restrict__ wim,
    const int mode,
    float* __restrict__ qre, float* __restrict__ qim)
{
    __shared__ unsigned sG[2][2 * 3840];   // 60 KB
    const int tid = threadIdx.x;
    const int lane = tid & 63, wid = tid >> 6;         // wid 0..8
    const int l15 = lane & 15, q = lane >> 4;
    const int m = (blockIdx.x * 9 + wid) * 16 + l15;
    const float2 kk = *(const float2*)(traj + 2 * m);
    float kxh, kxl, kyh, kyl;
    ksplit(kk.x, kxh, kxl);
    ksplit(kk.y, kyh, kyl);

    f32x4 tre[12], tim[12];
    #pragma unroll
    for (int i = 0; i < 12; ++i) {
        tre[i] = (f32x4){0.f, 0.f, 0.f, 0.f};
        tim[i] = (f32x4){0.f, 0.f, 0.f, 0.f};
    }

    float bc, bs;
    { const float ph = redphase(kyh, kyl, (float)(q * 4 - 96)); 
      bc = __builtin_amdgcn_cosf(ph); bs = __builtin_amdgcn_sinf(ph); }
    const float r1c = __builtin_amdgcn_cosf(kk.y), r1s = __builtin_amdgcn_sinf(kk.y);
    float r16c, r16s;
    { float g = kk.y * 16.f; g -= rintf(g);
      r16c = __builtin_amdgcn_cosf(g); r16s = __builtin_amdgcn_sinf(g); }

    u32x4 st[3];
    fw_stage_load(Ghi, Glo, tid, 0, st);
    fw_stage_write(&sG[0][0], tid, st);
    __syncthreads();

    for (int ch = 0; ch < 12; ++ch) {
        if (ch < 11) fw_stage_load(Ghi, Glo, tid, (ch + 1) * 16, st);

        u32x4 Ph, Pl, Qh, Ql;
        {
            float c = bc, s = bs;
            #pragma unroll
            for (int r = 0; r < 4; ++r) {
                unsigned h, l; split_pk(c, s, h, l);
                Ph[r] = h; Pl[r] = l;
                Qh[r] = rot16(h) ^ 0x00008000u;
                Ql[r] = rot16(l) ^ 0x00008000u;
                const float nc = c * r1c - s * r1s, ns = s * r1c + c * r1s;
                c = nc; s = ns;
            }
            const float nbc = bc * r16c - bs * r16s, nbs = bs * r16c + bc * r16s;
            bc = nbc; bs = nbs;
        }

        const unsigned* sb = &sG[ch & 1][0];
        #pragma unroll
        for (int si = 0; si < 12; ++si) {
            const int base = (si * 16 + l15) * 20 + q * 4;
            const u32x4 gh = *(const u32x4*)(sb + base);
            const u32x4 gl = *(const u32x4*)(sb + 3840 + base);
            tre[si] = mfma_bf16(gh, Ph, tre[si]);
            tre[si] = mfma_bf16(gh, Pl, tre[si]);
            tre[si] = mfma_bf16(gl, Ph, tre[si]);
            tim[si] = mfma_bf16(gh, Qh, tim[si]);
            tim[si] = mfma_bf16(gh, Ql, tim[si]);
            tim[si] = mfma_bf16(gl, Qh, tim[si]);
        }

        if (ch < 11) {
            __syncthreads();
            fw_stage_write(&sG[(ch + 1) & 1][0], tid, st);
            __syncthreads();
        }
    }

    float qr = 0.f, qi = 0.f;
    {
        float g = kk.x * 16.f; g -= rintf(g);
        const float rc = __builtin_amdgcn_cosf(g), rs = __builtin_amdgcn_sinf(g);
        #pragma unroll
        for (int rg = 0; rg < 4; ++rg) {
            const float ph = redphase(kxh, kxl, (float)(q * 4 + rg - 96));
            float c = __builtin_amdgcn_cosf(ph), s = __builtin_amdgcn_sinf(ph);
            #pragma unroll
            for (int si = 0; si < 12; ++si) {
                const float tr = tre[si][rg], ti = tim[si][rg];
                qr += c * tr + s * ti;
                qi += c * ti - s * tr;
                const float nc = c * rc - s * rs, ns = s * rc + c * rs;
                c = nc; s = ns;
            }
        }
    }
    qr += __shfl_xor(qr, 16); qi += __shfl_xor(qi, 16);
    qr += __shfl_xor(qr, 32); qi += __shfl_xor(qi, 32);
    if (lane < 16) {
        if (mode == 0) {
            const float den = fmaxf(sqrtf(qr * qr + qi * qi), 1e-20f);
            wre[m] /= den; wim[m] /= den;
        } else {
            const float sc = sqrtf(wre[m] * wre[m] + wim[m] * wim[m]);
            qre[m] = qr * sc; qim[m] = qi * sc;
        }
    }
}

// ---------------------------------------------------------------------------
__global__ void presplit_k(const float* __restrict__ re, const float* __restrict__ im,
                           unsigned* __restrict__ Gh, unsigned* __restrict__ Gl) {
    const int e = blockIdx.x * 256 + threadIdx.x;
    unsigned h, l;
    split_pk(re[e], im[e], h, l);     // low16 = re (even K), high16 = im (odd K)
    Gh[e] = h; Gl[e] = l;
}

// ---------------------------------------------------------------------------
extern "C" void kernel_launch(void* const* d_in, const int* in_sizes, int n_in,
                              void* d_out, int out_size, void* d_ws, size_t ws_size,
                              hipStream_t stream)
{
    const float* xin  = (const float*)d_in[0];   // (2,192,192)
    const float* traj = (const float*)d_in[1];   // (36864,2)
    float* out = (float*)d_out;                  // (2,192,192)

    char* pb = (char*)d_ws;
    unsigned* Aph = (unsigned*)pb; pb += (size_t)MTOT * NPIX * 4;
    unsigned* Apl = (unsigned*)pb; pb += (size_t)MTOT * NPIX * 4;
    float* ImRe = (float*)pb; pb += MTOT * 4;    // ImRe+ImIm contiguous (one memset)
    float* ImIm = (float*)pb; pb += MTOT * 4;
    float* wr   = (float*)pb; pb += MTOT * 4;
    float* wi   = (float*)pb; pb += MTOT * 4;
    float* dre  = (float*)pb; pb += MTOT * 4;
    float* dim_ = (float*)pb; pb += MTOT * 4;
    unsigned* Ghi = (unsigned*)pb; pb += MTOT * 4;
    unsigned* Glo = (unsigned*)pb; pb += MTOT * 4;

    precompA_k<<<dim3(MTOT / 256, NPIX), 256, 0, stream>>>(traj, Aph, Apl);
    winit_k<<<MTOT / 256, 256, 0, stream>>>(wr, wi);

    for (int it = 0; it < 3; ++it) {
        hipMemsetAsync(ImRe, 0, 2 * MTOT * sizeof(float), stream);
        adj_mfma_k<<<dim3(36, SPLITS / 4), 256, 0, stream>>>(traj, wr, wi,
                                                             Aph, Apl, ImRe, ImIm);
        presplit_k<<<MTOT / 256, 256, 0, stream>>>(ImRe, ImIm, Ghi, Glo);
        fwdq_k<<<256, 576, 0, stream>>>(traj, Ghi, Glo, wr, wi, 0, dre, dim_);
    }

    presplit_k<<<MTOT / 256, 256, 0, stream>>>(xin, xin + MTOT, Ghi, Glo);
    fwdq_k<<<256, 576, 0, stream>>>(traj, Ghi, Glo, wr, wi, 1, dre, dim_);
    hipMemsetAsync(out, 0, 2 * MTOT * sizeof(float), stream);
    adj_mfma_k<<<dim3(36, SPLITS / 4), 256, 0, stream>>>(traj, dre, dim_,
                                                         Aph, Apl, out, out + MTOT);
}

// Round 7
// 612.791 us; speedup vs baseline: 1.3714x; 1.3714x over previous
//
#include <hip/hip_runtime.h>
#include <math.h>

// Radial NUFFT + Pipe-Menon density compensation, MI355X (gfx950).
// bf16 MFMA (16x16x32), 2-term hi/lo split (3 products). Round 7 = round-5
// (verified) with adj's A-path restructured to fwdq's verified staging
// pattern: chunk-contiguous A layout, cooperative double-buffered LDS
// staging, 8 waves/block sharing one K-split, PG=4 partial-image epilogue.

#define MTOT 36864      // N_SHOTS*N_SAMPLES == NPIX*NPIX
#define NPIX 192
#define SPLITS 256
#define MPS (MTOT / SPLITS)     // 144 m per split
#define ADJ_CHUNKS (MPS / 16)   // 9 chunks of 16 m (32 K) per split
#define PG 4                    // partial output images

typedef __attribute__((ext_vector_type(8))) short s16x8;
typedef __attribute__((ext_vector_type(4))) float f32x4;
typedef __attribute__((ext_vector_type(4))) unsigned u32x4;

__device__ __forceinline__ f32x4 mfma_bf16(u32x4 a, u32x4 b, f32x4 c) {
    return __builtin_amdgcn_mfma_f32_16x16x32_bf16(
        __builtin_bit_cast(s16x8, a), __builtin_bit_cast(s16x8, b), c, 0, 0, 0);
}

// Split (a,b) into packed bf16 pairs: hi = (bf16(a) | bf16(b)<<16), lo = residuals.
__device__ __forceinline__ void split_pk(float a, float b, unsigned &hi, unsigned &lo) {
    const unsigned ua = __float_as_uint(a), ub = __float_as_uint(b);
    const unsigned ha = (ua + 0x8000u) & 0xffff0000u;
    const unsigned hb = (ub + 0x8000u) & 0xffff0000u;
    hi = (ha >> 16) | hb;
    const float la = a - __uint_as_float(ha);
    const float lb = b - __uint_as_float(hb);
    lo = ((__float_as_uint(la) + 0x8000u) >> 16) |
         ((__float_as_uint(lb) + 0x8000u) & 0xffff0000u);
}

// k split into 12-bit hi + residual so kh*p (p integer, |p|<=96) is EXACT in fp32.
__device__ __forceinline__ void ksplit(float k, float &kh, float &kl) {
    kh = __uint_as_float(__float_as_uint(k) & 0xfffff000u);
    kl = k - kh;
}
__device__ __forceinline__ float redphase(float kh, float kl, float p) {
    float r = kh * p;
    r -= rintf(r);
    r = fmaf(kl, p, r);
    return r;                   // revolutions, |r| <= ~0.512
}
__device__ __forceinline__ unsigned rot16(unsigned v) {
    return __builtin_amdgcn_alignbit(v, v, 16);
}

// ---------------------------------------------------------------------------
// Precompute A = (cos, -sin) packed bf16 hi/lo, CHUNK-CONTIGUOUS layout:
// AS[mc][plane][x][mi], mc = m>>4, mi = m&15; chunk region = 6144 u32 = 24 KB.
__global__ void precompA_k(const float* __restrict__ traj,
                           unsigned* __restrict__ AS) {
    const int m = blockIdx.x * 256 + threadIdx.x;
    const int x = blockIdx.y;
    float kh, kl; ksplit(traj[2 * m], kh, kl);
    const float ph = redphase(kh, kl, (float)(x - 96));
    const float c = __builtin_amdgcn_cosf(ph);
    const float s = __builtin_amdgcn_sinf(ph);
    unsigned h, l; split_pk(c, -s, h, l);
    const int mc = m >> 4, mi = m & 15;
    AS[(size_t)mc * 6144 + x * 16 + mi]        = h;
    AS[(size_t)mc * 6144 + 3072 + x * 16 + mi] = l;
}

__global__ void winit_k(float* __restrict__ wr, float* __restrict__ wi) {
    const int m = blockIdx.x * 256 + threadIdx.x;
    wr[m] = 1.f; wi[m] = 0.f;
}

// ---------------------------------------------------------------------------
// Adjoint: out[x,y] += sum_m conj(A[m,x]) * d[m] * conj(B[m,y])
// Block: 8 waves, ALL same split s; tiles 4tx x 2ty (48x48 each, r5 core).
// A chunk (24 KB) staged cooperatively into double-buffered LDS; frag reads
// are fwdq's pad-20 ds_read_b128 pattern. Epilogue: global atomics into
// partial image (s & 3).
__global__ __launch_bounds__(512) void adj_mfma_k(
    const float* __restrict__ traj,
    const float* __restrict__ dre, const float* __restrict__ dim_,
    const unsigned* __restrict__ AS,
    float* __restrict__ outP)
{
    __shared__ unsigned sA[2][2 * 3840];           // 60 KB: [buf][plane][x][mi(pad20)]
    const int tid = threadIdx.x;
    const int lane = tid & 63, wid = tid >> 6;     // wid 0..7
    const int l15 = lane & 15, q = lane >> 4;
    const int wi = wid & 3, wj = wid >> 2;         // wave tile
    const int tx = wi * 48;
    const int ty = blockIdx.x * 96 + wj * 48;      // blockIdx.x = 0..1 (y half)
    const int s = blockIdx.y;                      // split 0..255
    float* outRe = outP + (size_t)(s & (PG - 1)) * (2 * MTOT);
    float* outIm = outRe + MTOT;

    f32x4 accRe[3][3], accIm[3][3];
    #pragma unroll
    for (int i = 0; i < 3; ++i)
        #pragma unroll
        for (int j = 0; j < 3; ++j) {
            accRe[i][j] = (f32x4){0.f, 0.f, 0.f, 0.f};
            accIm[i][j] = (f32x4){0.f, 0.f, 0.f, 0.f};
        }

    const float pyB = (float)(ty + l15 - 96);
    const unsigned* Abase = AS + (size_t)(s * ADJ_CHUNKS) * 6144;

    u32x4 st[3];
    // stage chunk 0
    #pragma unroll
    for (int j = 0; j < 3; ++j)
        st[j] = *(const u32x4*)(Abase + (tid + j * 512) * 4);
    #pragma unroll
    for (int j = 0; j < 3; ++j) {
        const int li = tid + j * 512;              // 0..1535
        const int pl = li / 768, rem = li - pl * 768;
        const int x = rem >> 2, wq = li & 3;
        *(u32x4*)(&sA[0][pl * 3840 + x * 20 + wq * 4]) = st[j];
    }
    __syncthreads();

    for (int ch = 0; ch < ADJ_CHUNKS; ++ch) {
        const int cur = ch & 1;
        if (ch + 1 < ADJ_CHUNKS) {
            const unsigned* src = Abase + (size_t)(ch + 1) * 6144;
            #pragma unroll
            for (int j = 0; j < 3; ++j)
                st[j] = *(const u32x4*)(src + (tid + j * 512) * 4);
        }

        // A fragments from LDS (hi plane 0, lo plane 1)
        u32x4 Ah[3], Al[3];
        #pragma unroll
        for (int si = 0; si < 3; ++si) {
            const int base = (tx + si * 16 + l15) * 20 + q * 4;
            Ah[si] = *(const u32x4*)(&sA[cur][base]);
            Al[si] = *(const u32x4*)(&sA[cur][3840 + base]);
        }

        // u = d*conj(B) for this lane's 4 m values (r5-verified path)
        const int mb = s * MPS + ch * 16 + q * 4;
        float ur[4], ui[4], ryc[4], rys[4];
        #pragma unroll
        for (int r = 0; r < 4; ++r) {
            const float ky = traj[2 * (mb + r) + 1];
            const float dr_ = dre[mb + r], di_ = dim_[mb + r];
            float kh, kl;
            ksplit(ky, kh, kl);
            const float ph = redphase(kh, kl, pyB);
            const float cb = __builtin_amdgcn_cosf(ph), sb = __builtin_amdgcn_sinf(ph);
            ur[r] = dr_ * cb - di_ * sb;           // u_re
            ui[r] = di_ * cb + dr_ * sb;           // u_im
            float g = ky * 16.f; g -= rintf(g);
            ryc[r] = __builtin_amdgcn_cosf(g); rys[r] = __builtin_amdgcn_sinf(g);
        }
        #pragma unroll
        for (int sj = 0; sj < 3; ++sj) {
            u32x4 Ph, Pl, Qh, Ql;
            #pragma unroll
            for (int r = 0; r < 4; ++r) {
                unsigned h, l; split_pk(ur[r], ui[r], h, l);
                Ph[r] = h; Pl[r] = l;
                Qh[r] = rot16(h) ^ 0x80000000u;    // (u_im, -u_re)
                Ql[r] = rot16(l) ^ 0x80000000u;
                const float nr = ur[r] * ryc[r] - ui[r] * rys[r];
                const float ni = ui[r] * ryc[r] + ur[r] * rys[r];
                ur[r] = nr; ui[r] = ni;
            }
            #pragma unroll
            for (int si = 0; si < 3; ++si) {
                accRe[si][sj] = mfma_bf16(Ah[si], Ph, accRe[si][sj]);
                accRe[si][sj] = mfma_bf16(Ah[si], Pl, accRe[si][sj]);
                accRe[si][sj] = mfma_bf16(Al[si], Ph, accRe[si][sj]);
                accIm[si][sj] = mfma_bf16(Ah[si], Qh, accIm[si][sj]);
                accIm[si][sj] = mfma_bf16(Ah[si], Ql, accIm[si][sj]);
                accIm[si][sj] = mfma_bf16(Al[si], Qh, accIm[si][sj]);
            }
        }

        if (ch + 1 < ADJ_CHUNKS) {
            __syncthreads();
            #pragma unroll
            for (int j = 0; j < 3; ++j) {
                const int li = tid + j * 512;
                const int pl = li / 768, rem = li - pl * 768;
                const int x = rem >> 2, wq = li & 3;
                *(u32x4*)(&sA[cur ^ 1][pl * 3840 + x * 20 + wq * 4]) = st[j];
            }
            __syncthreads();
        }
    }

    // epilogue: direct global atomics into partial image (coalesced 16-y runs)
    #pragma unroll
    for (int si = 0; si < 3; ++si)
        #pragma unroll
        for (int sj = 0; sj < 3; ++sj)
            #pragma unroll
            for (int rg = 0; rg < 4; ++rg) {
                const int x = tx + si * 16 + q * 4 + rg;   // C/D row = quad*4+reg
                const int y = ty + sj * 16 + l15;          // C/D col = lane&15
                atomicAdd(outRe + x * NPIX + y, accRe[si][sj][rg]);
                atomicAdd(outIm + x * NPIX + y, accIm[si][sj][rg]);
            }
}

// ---------------------------------------------------------------------------
// fwdq: q[m] = sum_x A[m,x] * (sum_y B[m,y]*g[x,y]).   (unchanged from r5)
__device__ __forceinline__ void fw_stage_load(const unsigned* __restrict__ Ghi,
                                              const unsigned* __restrict__ Glo,
                                              int tid, int koff, u32x4 st[3]) {
    #pragma unroll
    for (int j = 0; j < 3; ++j) {
        const int li = tid + j * 576;
        if (li < 1536) {
            const int row = li >> 3, pl = (li >> 2) & 1, qt = li & 3;
            const unsigned* src = pl ? Glo : Ghi;
            st[j] = *(const u32x4*)(src + row * 192 + koff + qt * 4);
        }
    }
}
__device__ __forceinline__ void fw_stage_write(unsigned* sb, int tid, const u32x4 st[3]) {
    #pragma unroll
    for (int j = 0; j < 3; ++j) {
        const int li = tid + j * 576;
        if (li < 1536) {
            const int row = li >> 3, pl = (li >> 2) & 1, qt = li & 3;
            *(u32x4*)(sb + pl * 3840 + row * 20 + qt * 4) = st[j];
        }
    }
}

__global__ __launch_bounds__(576) void fwdq_k(
    const float* __restrict__ traj,
    const unsigned* __restrict__ Ghi, const unsigned* __restrict__ Glo,
    float* __restrict__ wre, float* __restrict__ wim,
    const int mode,
    float* __restrict__ qre, float* __restrict__ qim)
{
    __shared__ unsigned sG[2][2 * 3840];   // 60 KB
    const int tid = threadIdx.x;
    const int lane = tid & 63, wid = tid >> 6;         // wid 0..8
    const int l15 = lane & 15, q = lane >> 4;
    const int m = (blockIdx.x * 9 + wid) * 16 + l15;
    const float2 kk = *(const float2*)(traj + 2 * m);
    float kxh, kxl, kyh, kyl;
    ksplit(kk.x, kxh, kxl);
    ksplit(kk.y, kyh, kyl);

    f32x4 tre[12], tim[12];
    #pragma unroll
    for (int i = 0; i < 12; ++i) {
        tre[i] = (f32x4){0.f, 0.f, 0.f, 0.f};
        tim[i] = (f32x4){0.f, 0.f, 0.f, 0.f};
    }

    float bc, bs;
    { const float ph = redphase(kyh, kyl, (float)(q * 4 - 96)); 
      bc = __builtin_amdgcn_cosf(ph); bs = __builtin_amdgcn_sinf(ph); }
    const float r1c = __builtin_amdgcn_cosf(kk.y), r1s = __builtin_amdgcn_sinf(kk.y);
    float r16c, r16s;
    { float g = kk.y * 16.f; g -= rintf(g);
      r16c = __builtin_amdgcn_cosf(g); r16s = __builtin_amdgcn_sinf(g); }

    u32x4 st[3];
    fw_stage_load(Ghi, Glo, tid, 0, st);
    fw_stage_write(&sG[0][0], tid, st);
    __syncthreads();

    for (int ch = 0; ch < 12; ++ch) {
        if (ch < 11) fw_stage_load(Ghi, Glo, tid, (ch + 1) * 16, st);

        u32x4 Ph, Pl, Qh, Ql;
        {
            float c = bc, s = bs;
            #pragma unroll
            for (int r = 0; r < 4; ++r) {
                unsigned h, l; split_pk(c, s, h, l);
                Ph[r] = h; Pl[r] = l;
                Qh[r] = rot16(h) ^ 0x00008000u;
                Ql[r] = rot16(l) ^ 0x00008000u;
                const float nc = c * r1c - s * r1s, ns = s * r1c + c * r1s;
                c = nc; s = ns;
            }
            const float nbc = bc * r16c - bs * r16s, nbs = bs * r16c + bc * r16s;
            bc = nbc; bs = nbs;
        }

        const unsigned* sb = &sG[ch & 1][0];
        #pragma unroll
        for (int si = 0; si < 12; ++si) {
            const int base = (si * 16 + l15) * 20 + q * 4;
            const u32x4 gh = *(const u32x4*)(sb + base);
            const u32x4 gl = *(const u32x4*)(sb + 3840 + base);
            tre[si] = mfma_bf16(gh, Ph, tre[si]);
            tre[si] = mfma_bf16(gh, Pl, tre[si]);
            tre[si] = mfma_bf16(gl, Ph, tre[si]);
            tim[si] = mfma_bf16(gh, Qh, tim[si]);
            tim[si] = mfma_bf16(gh, Ql, tim[si]);
            tim[si] = mfma_bf16(gl, Qh, tim[si]);
        }

        if (ch < 11) {
            __syncthreads();
            fw_stage_write(&sG[(ch + 1) & 1][0], tid, st);
            __syncthreads();
        }
    }

    float qr = 0.f, qi = 0.f;
    {
        float g = kk.x * 16.f; g -= rintf(g);
        const float rc = __builtin_amdgcn_cosf(g), rs = __builtin_amdgcn_sinf(g);
        #pragma unroll
        for (int rg = 0; rg < 4; ++rg) {
            const float ph = redphase(kxh, kxl, (float)(q * 4 + rg - 96));
            float c = __builtin_amdgcn_cosf(ph), s = __builtin_amdgcn_sinf(ph);
            #pragma unroll
            for (int si = 0; si < 12; ++si) {
                const float tr = tre[si][rg], ti = tim[si][rg];
                qr += c * tr + s * ti;
                qi += c * ti - s * tr;
                const float nc = c * rc - s * rs, ns = s * rc + c * rs;
                c = nc; s = ns;
            }
        }
    }
    qr += __shfl_xor(qr, 16); qi += __shfl_xor(qi, 16);
    qr += __shfl_xor(qr, 32); qi += __shfl_xor(qi, 32);
    if (lane < 16) {
        if (mode == 0) {
            const float den = fmaxf(sqrtf(qr * qr + qi * qi), 1e-20f);
            wre[m] /= den; wim[m] /= den;
        } else {
            const float sc = sqrtf(wre[m] * wre[m] + wim[m] * wim[m]);
            qre[m] = qr * sc; qim[m] = qi * sc;
        }
    }
}

// ---------------------------------------------------------------------------
__global__ void presplit_k(const float* __restrict__ re, const float* __restrict__ im,
                           unsigned* __restrict__ Gh, unsigned* __restrict__ Gl) {
    const int e = blockIdx.x * 256 + threadIdx.x;
    unsigned h, l;
    split_pk(re[e], im[e], h, l);     // low16 = re (even K), high16 = im (odd K)
    Gh[e] = h; Gl[e] = l;
}

// Reduce PG partial images + presplit (pipe path)
__global__ void presplitP_k(const float* __restrict__ outP,
                            unsigned* __restrict__ Gh, unsigned* __restrict__ Gl) {
    const int e = blockIdx.x * 256 + threadIdx.x;
    float re = 0.f, im = 0.f;
    #pragma unroll
    for (int g = 0; g < PG; ++g) {
        re += outP[(size_t)g * (2 * MTOT) + e];
        im += outP[(size_t)g * (2 * MTOT) + MTOT + e];
    }
    unsigned h, l;
    split_pk(re, im, h, l);
    Gh[e] = h; Gl[e] = l;
}

// Reduce PG partial images -> final output
__global__ void reduceOut_k(const float* __restrict__ outP, float* __restrict__ out) {
    const int e = blockIdx.x * 256 + threadIdx.x;
    float re = 0.f, im = 0.f;
    #pragma unroll
    for (int g = 0; g < PG; ++g) {
        re += outP[(size_t)g * (2 * MTOT) + e];
        im += outP[(size_t)g * (2 * MTOT) + MTOT + e];
    }
    out[e] = re; out[MTOT + e] = im;
}

// ---------------------------------------------------------------------------
extern "C" void kernel_launch(void* const* d_in, const int* in_sizes, int n_in,
                              void* d_out, int out_size, void* d_ws, size_t ws_size,
                              hipStream_t stream)
{
    const float* xin  = (const float*)d_in[0];   // (2,192,192)
    const float* traj = (const float*)d_in[1];   // (36864,2)
    float* out = (float*)d_out;                  // (2,192,192)

    char* pb = (char*)d_ws;
    unsigned* AS = (unsigned*)pb; pb += (size_t)2304 * 6144 * 4;   // 56.6 MB
    float* outP = (float*)pb; pb += (size_t)PG * 2 * MTOT * 4;
    float* wr   = (float*)pb; pb += MTOT * 4;
    float* wi   = (float*)pb; pb += MTOT * 4;
    float* dre  = (float*)pb; pb += MTOT * 4;
    float* dim_ = (float*)pb; pb += MTOT * 4;
    unsigned* Ghi = (unsigned*)pb; pb += MTOT * 4;
    unsigned* Glo = (unsigned*)pb; pb += MTOT * 4;

    precompA_k<<<dim3(MTOT / 256, NPIX), 256, 0, stream>>>(traj, AS);
    winit_k<<<MTOT / 256, 256, 0, stream>>>(wr, wi);

    for (int it = 0; it < 3; ++it) {
        hipMemsetAsync(outP, 0, (size_t)PG * 2 * MTOT * 4, stream);
        adj_mfma_k<<<dim3(2, SPLITS), 512, 0, stream>>>(traj, wr, wi, AS, outP);
        presplitP_k<<<MTOT / 256, 256, 0, stream>>>(outP, Ghi, Glo);
        fwdq_k<<<256, 576, 0, stream>>>(traj, Ghi, Glo, wr, wi, 0, dre, dim_);
    }

    presplit_k<<<MTOT / 256, 256, 0, stream>>>(xin, xin + MTOT, Ghi, Glo);
    fwdq_k<<<256, 576, 0, stream>>>(traj, Ghi, Glo, wr, wi, 1, dre, dim_);
    hipMemsetAsync(outP, 0, (size_t)PG * 2 * MTOT * 4, stream);
    adj_mfma_k<<<dim3(2, SPLITS), 512, 0, stream>>>(traj, dre, dim_, AS, outP);
    reduceOut_k<<<MTOT / 256, 256, 0, stream>>>(outP, out);
}